// Round 9
// baseline (701.960 us; speedup 1.0000x reference)
//
#include <hip/hip_runtime.h>

// Problem constants (from reference)
#define TV_ 2048
#define NB_ 16
#define NV_ 1024
#define TK_ 2048
#define NK_ 1024

typedef float    f32x4  __attribute__((ext_vector_type(4)));
typedef float    f32x16 __attribute__((ext_vector_type(16)));
typedef float    fl4    __attribute__((ext_vector_type(4)));
typedef _Float16 hfx8   __attribute__((ext_vector_type(8)));
typedef ushort   us8    __attribute__((ext_vector_type(8)));

static __device__ __forceinline__ ushort f2h(float f){
  _Float16 h = (_Float16)f;               // RN-even
  return __builtin_bit_cast(ushort, h);
}
static __device__ __forceinline__ float h2f(ushort u){
  return (float)__builtin_bit_cast(_Float16, u);
}

// ---------------- elementwise convert: fp32 -> fp16 ----------------
__global__ __launch_bounds__(256) void cvt_h_k(const float* __restrict__ x,
                                               ushort* __restrict__ y, long n4){
  long i = (long)blockIdx.x*256 + threadIdx.x;
  const long stride = (long)gridDim.x*256;
  for (; i < n4; i += stride){
    fl4 v = ((const fl4*)x)[i];
    ((ushort4*)y)[i] = make_ushort4(f2h(v[0]), f2h(v[1]), f2h(v[2]), f2h(v[3]));
  }
}

// ---------------- w [K,V] -> wT [V,K] fp16 ----------------
__global__ void wtrans_k(const float* __restrict__ w, ushort* __restrict__ wT){
  __shared__ float t[32][33];
  const int tx = threadIdx.x, ty = threadIdx.y;       // 32 x 8
  const int k0 = blockIdx.x*32, v0 = blockIdx.y*32;
#pragma unroll
  for (int r=0;r<4;++r) t[ty+8*r][tx] = w[(long)(k0+ty+8*r)*NV_ + v0+tx];
  __syncthreads();
#pragma unroll
  for (int r=0;r<4;++r)
    wT[(long)(v0+ty+8*r)*NK_ + k0+tx] = f2h(t[tx][ty+8*r]);
}

// ------- values [Tv,B,V] -> v2 [B,Tv,V] fp16 AND vbt [B,V,Tv] fp16, one read -------
__global__ void vboth_k(const float* __restrict__ vals,
                        ushort* __restrict__ v2, ushort* __restrict__ vbt){
  __shared__ float t[32][33];
  const int tx = threadIdx.x, ty = threadIdx.y;       // 32 x 8
  const int s0 = blockIdx.x*32, v0 = blockIdx.y*32, b = blockIdx.z;
#pragma unroll
  for (int r=0;r<4;++r){
    float x = vals[((long)(s0+ty+8*r)*NB_ + b)*NV_ + v0+tx];
    t[ty+8*r][tx] = x;
    v2[((long)b*TV_ + s0+ty+8*r)*NV_ + v0+tx] = f2h(x);
  }
  __syncthreads();
#pragma unroll
  for (int r=0;r<4;++r)
    vbt[((long)b*NV_ + v0+ty+8*r)*TV_ + s0+tx] = f2h(t[tx][ty+8*r]);
}

// =======================================================================
// 256x256 8-phase GEMM, now with 32x32x16 MFMA (µbench 2178 vs 1955 TF).
// Same staging/vmcnt schedule as the R4-verified kernel; only the LDS
// fragment addressing, MFMA shape and epilogue C/D mapping change.
// LDS swizzle: slot ^= (r&7) ^ ((r>>2)&6)  — extended so each 8-lane
// service group of a 32-row frag read covers all 8 bank-quads.
// Applied on the staging SOURCE address and unwound at ds_read (rule #21).
// =======================================================================
static __device__ __forceinline__ hfx8 ldfrag32(const ushort* base, int r, int g){
  // g = global 16B-slot (subk*2 + lane>>5); r = row (0..127)
  const int slot = (g ^ (r & 7) ^ ((r >> 2) & 6)) & 7;
  return *(const hfx8*)((const char*)base + r*128 + (slot << 4));
}

#define SAOFF(b,h) (((b)*2+(h))*8192)
#define SBOFF(b,h) (32768 + ((b)*2+(h))*8192)

#define STAGE(Xp, hb, t, ldsoff) do { \
  _Pragma("unroll") \
  for (int c_=0;c_<2;++c_) \
    __builtin_amdgcn_global_load_lds( \
      (const __attribute__((address_space(1))) unsigned*)((Xp) + (long)(hb)*128*K + (long)(t)*64 + soff[c_]), \
      (__attribute__((address_space(3))) unsigned*)(lds + (ldsoff) + chunk0[c_]*8), 16, 0, 0); \
} while(0)

#define VM4  asm volatile("s_waitcnt vmcnt(4)"  ::: "memory")
#define VM0  asm volatile("s_waitcnt vmcnt(0)"  ::: "memory")
#define NOPS (void)0

#define BARR() do { __builtin_amdgcn_s_barrier(); __builtin_amdgcn_sched_barrier(0); } while(0)

#define MFMA32(I0, JB, BREG) \
  _Pragma("unroll") for (int s_=0;s_<4;++s_) \
  _Pragma("unroll") for (int i_=0;i_<2;++i_) \
    acc32[(I0)+i_][JB] = __builtin_amdgcn_mfma_f32_32x32x16_f16(aF[i_][s_], BREG[s_], acc32[(I0)+i_][JB], 0,0,0)

// One K-tile = 4 phases. Quadrant walk: (i01,j0) (i01,j1) (i23,j1) (i23,j0);
// bj0 register-cached across the tile (as b01 was in the 16x16 version).
#define KTILE(BUF, S0, S1, S2, S3, EW) do { \
  const ushort* sa_ = lds + SAOFF(BUF, wr); \
  const ushort* sb_ = lds + SBOFF(BUF, (wc>>1)); \
  const int brow_ = (wc&1)*64; \
  /* PH0: read aF(i0,i1), bj0 ; mfma i01 x j0 */ \
  _Pragma("unroll") for (int i_=0;i_<2;++i_) _Pragma("unroll") for (int s_=0;s_<4;++s_) \
    aF[i_][s_] = ldfrag32(sa_, i_*32 + l31, s_*2 + lhi); \
  _Pragma("unroll") for (int s_=0;s_<4;++s_) \
    bj0[s_] = ldfrag32(sb_, brow_ + l31, s_*2 + lhi); \
  S0; \
  BARR(); \
  __builtin_amdgcn_s_setprio(1); \
  MFMA32(0, 0, bj0); \
  __builtin_amdgcn_s_setprio(0); \
  BARR(); \
  /* PH1: read bj1 ; mfma i01 x j1 */ \
  _Pragma("unroll") for (int s_=0;s_<4;++s_) \
    bj1[s_] = ldfrag32(sb_, brow_ + 32 + l31, s_*2 + lhi); \
  S1; \
  BARR(); \
  __builtin_amdgcn_s_setprio(1); \
  MFMA32(0, 1, bj1); \
  __builtin_amdgcn_s_setprio(0); \
  BARR(); \
  /* PH2: read aF(i2,i3) ; mfma i23 x j1 */ \
  _Pragma("unroll") for (int i_=0;i_<2;++i_) _Pragma("unroll") for (int s_=0;s_<4;++s_) \
    aF[i_][s_] = ldfrag32(sa_, (2+i_)*32 + l31, s_*2 + lhi); \
  S2; \
  BARR(); \
  __builtin_amdgcn_s_setprio(1); \
  MFMA32(2, 1, bj1); \
  __builtin_amdgcn_s_setprio(0); \
  BARR(); \
  /* PH3: (bj0 cached) ; mfma i23 x j0 */ \
  S3; \
  BARR(); \
  __builtin_amdgcn_s_setprio(1); \
  MFMA32(2, 0, bj0); \
  __builtin_amdgcn_s_setprio(0); \
  EW; \
  BARR(); \
} while(0)

// ---------------- generic GEMM ----------------
// OUTMODE: 0 = fp32 C; 1 = fp16 Ch; 2 = fp16 Ch shifted by per-wave 64-col max
//          + softmax partials (pm, ps).
template<int OUTMODE>
__global__ __launch_bounds__(512, 2)
void gemm8_k(const ushort* __restrict__ A, const ushort* __restrict__ BT,
             float* __restrict__ C, ushort* __restrict__ Ch,
             float* __restrict__ pm, float* __restrict__ ps,
             int N, int K, long sA, long sB, long sC)
{
  extern __shared__ ushort lds[];

  const int tid  = threadIdx.x;
  const int lane = tid & 63;
  const int w    = tid >> 6;
  const int wr   = w >> 2;
  const int wc   = w & 3;
  const int l31  = lane & 31, lhi = lane >> 5;
  const int bz   = blockIdx.z;
  const long m0  = (long)blockIdx.y * 256;
  const long n0  = (long)blockIdx.x * 256;

  const ushort* Ap = A  + (long)bz*sA + m0*K;
  const ushort* Bp = BT + (long)bz*sB + n0*K;

  int chunk0[2], soff[2];
#pragma unroll
  for (int c=0;c<2;++c){
    chunk0[c] = (w<<7) + (c<<6);
    const int idx = chunk0[c] + lane;
    const int row = idx >> 3, sl = idx & 7;
    soff[c] = row*K + (((sl ^ (row & 7) ^ ((row >> 2) & 6)) & 7) << 3);
  }

  f32x16 acc32[4][2];
#pragma unroll
  for (int i=0;i<4;++i)
#pragma unroll
    for (int j=0;j<2;++j)
#pragma unroll
      for (int r=0;r<16;++r) acc32[i][j][r] = 0.f;

  hfx8 aF[2][4], bj0[4], bj1[4];

  const int NT = K >> 6;

  STAGE(Ap, 0, 0, SAOFF(0,0));
  STAGE(Ap, 1, 0, SAOFF(0,1));
  STAGE(Bp, 0, 0, SBOFF(0,0));
  STAGE(Bp, 1, 0, SBOFF(0,1));
  STAGE(Bp, 0, 1, SBOFF(1,0));
  STAGE(Ap, 0, 1, SAOFF(1,0));
  VM4;
  BARR();

  for (int u=0; u <= NT-4; u+=2){
    KTILE(0,
          STAGE(Ap, 1, u+1, SAOFF(1,1)),
          STAGE(Bp, 1, u+1, SBOFF(1,1)),
          STAGE(Bp, 0, u+2, SBOFF(0,0)),
          STAGE(Ap, 0, u+2, SAOFF(0,0)),
          VM4);
    KTILE(1,
          STAGE(Ap, 1, u+2, SAOFF(0,1)),
          STAGE(Bp, 1, u+2, SBOFF(0,1)),
          STAGE(Bp, 0, u+3, SBOFF(1,0)),
          STAGE(Ap, 0, u+3, SAOFF(1,0)),
          VM4);
  }
  KTILE(0,
        STAGE(Ap, 1, NT-1, SAOFF(1,1)),
        STAGE(Bp, 1, NT-1, SBOFF(1,1)),
        NOPS, NOPS, VM0);
  KTILE(1, NOPS, NOPS, NOPS, NOPS, NOPS);

  // Epilogue. 32x32 C/D map (m74/m101-verified): col = lane&31,
  // row = (reg&3) + 8*(reg>>2) + 4*(lane>>5).
  const long cb = (long)bz*sC;
  if constexpr (OUTMODE == 2){
#pragma unroll
    for (int i=0;i<4;++i){
      float mts[16];
#pragma unroll
      for (int r=0;r<16;++r){
        float mt = fmaxf(acc32[i][0][r], acc32[i][1][r]);
#pragma unroll
        for (int off=1; off<32; off<<=1) mt = fmaxf(mt, __shfl_xor(mt, off));
        float se = __expf(acc32[i][0][r] - mt) + __expf(acc32[i][1][r] - mt);
#pragma unroll
        for (int off=1; off<32; off<<=1) se += __shfl_xor(se, off);
        if (l31 == 0){
          const int row = (r&3) + 8*(r>>2) + 4*lhi;
          const long rg = (long)bz*TK_ + m0 + wr*128 + i*32 + row;
          pm[rg*32 + blockIdx.x*4 + wc] = mt;
          ps[rg*32 + blockIdx.x*4 + wc] = se;
        }
        mts[r] = mt;
      }
#pragma unroll
      for (int j=0;j<2;++j)
#pragma unroll
        for (int r=0;r<16;++r){
          const int row = (r&3) + 8*(r>>2) + 4*lhi;
          const long gm = m0 + wr*128 + i*32 + row;
          const long gn = n0 + wc*64  + j*32 + l31;
          Ch[cb + gm*N + gn] = f2h(acc32[i][j][r] - mts[r]);
        }
    }
  } else {
#pragma unroll
    for (int i=0;i<4;++i)
#pragma unroll
      for (int j=0;j<2;++j)
#pragma unroll
        for (int r=0;r<16;++r){
          const int row = (r&3) + 8*(r>>2) + 4*lhi;
          const long gm = m0 + wr*128 + i*32 + row;
          const long gn = n0 + wc*64  + j*32 + l31;
          const long o = cb + gm*N + gn;
          if constexpr (OUTMODE == 1) Ch[o] = f2h(acc32[i][j][r]);
          else                        C[o]  = acc32[i][j][r];
        }
  }
}

// ---- row-stat reduce: 32 (max,sumexp) partials -> dsh2[r][p] = mt - m - ln(s) ----
__global__ __launch_bounds__(256) void rs_k(const float* __restrict__ pm,
                                            const float* __restrict__ ps,
                                            float* __restrict__ dsh2){
  const long r = (long)blockIdx.x*256 + threadIdx.x;   // 32768 rows
  float pmv[32];
  float m = -3.4e38f;
#pragma unroll
  for (int p=0;p<32;++p){ pmv[p] = pm[r*32+p]; m = fmaxf(m, pmv[p]); }
  float s = 0.f;
#pragma unroll
  for (int p=0;p<32;++p) s += ps[r*32+p] * __expf(pmv[p] - m);
  const float lg = __logf(s);
#pragma unroll
  for (int p=0;p<32;++p) dsh2[r*32+p] = pmv[p] - m - lg;
}

// ---- streaming exp pass: P = exp(h + dsh2); writes attn fp32 + P16 fp16 ----
__global__ __launch_bounds__(256) void pexp_k(const ushort* __restrict__ h16,
                                              const float* __restrict__ dsh2,
                                              float* __restrict__ attn,
                                              ushort* __restrict__ p16){
  const long n8 = (long)NB_*TK_*TV_/8;
  long i = (long)blockIdx.x*256 + threadIdx.x;
  const long stride = (long)gridDim.x*256;
  for (; i < n8; i += stride){
    us8 hv = ((const us8*)h16)[i];
    const long row = i >> 8;               // Tv/8 = 256 8-elem chunks per row
    const int  c8  = (int)(i & 255);
    const float d = dsh2[row*32 + (c8>>3)];
    float p[8];
#pragma unroll
    for (int e=0;e<8;++e) p[e] = __expf(h2f((ushort)hv[e]) + d);
    fl4 q0 = {p[0],p[1],p[2],p[3]}, q1 = {p[4],p[5],p[6],p[7]};
    *(fl4*)(attn + i*8)     = q0;
    *(fl4*)(attn + i*8 + 4) = q1;
    us8 o;
#pragma unroll
    for (int e=0;e<8;++e) o[e] = f2h(p[e]);
    ((us8*)p16)[i] = o;
  }
}

// ---------------- row softmax (fallback path only) ----------------
__global__ __launch_bounds__(256) void softmax_k(float* __restrict__ lg, ushort* __restrict__ pb){
  const long base = (long)blockIdx.x * TV_;
  const int tid = threadIdx.x;
  const int lane = tid & 63, w = tid >> 6;
  float x[8];
  fl4 a = *(const fl4*)(lg + base + tid*8);
  fl4 b = *(const fl4*)(lg + base + tid*8 + 4);
  x[0]=a[0];x[1]=a[1];x[2]=a[2];x[3]=a[3];x[4]=b[0];x[5]=b[1];x[6]=b[2];x[7]=b[3];
  float m = x[0];
#pragma unroll
  for (int j=1;j<8;++j) m = fmaxf(m, x[j]);
#pragma unroll
  for (int off=32; off; off>>=1) m = fmaxf(m, __shfl_xor(m, off));
  __shared__ float rm[4], rs[4];
  if (lane==0) rm[w]=m;
  __syncthreads();
  m = fmaxf(fmaxf(rm[0],rm[1]), fmaxf(rm[2],rm[3]));
  float s = 0.f;
#pragma unroll
  for (int j=0;j<8;++j){ x[j] = __expf(x[j]-m); s += x[j]; }
#pragma unroll
  for (int off=32; off; off>>=1) s += __shfl_xor(s, off);
  if (lane==0) rs[w]=s;
  __syncthreads();
  s = rs[0]+rs[1]+rs[2]+rs[3];
  const float inv = 1.f/s;
  fl4 p0 = {x[0]*inv, x[1]*inv, x[2]*inv, x[3]*inv};
  fl4 p1 = {x[4]*inv, x[5]*inv, x[6]*inv, x[7]*inv};
  *(fl4*)(lg + base + tid*8)     = p0;
  *(fl4*)(lg + base + tid*8 + 4) = p1;
  *(ushort4*)(pb + base + tid*8)     = make_ushort4(f2h(p0[0]),f2h(p0[1]),f2h(p0[2]),f2h(p0[3]));
  *(ushort4*)(pb + base + tid*8 + 4) = make_ushort4(f2h(p1[0]),f2h(p1[1]),f2h(p1[2]),f2h(p1[3]));
}

extern "C" void kernel_launch(void* const* d_in, const int* in_sizes, int n_in,
                              void* d_out, int out_size, void* d_ws, size_t ws_size,
                              hipStream_t stream){
  (void)in_sizes; (void)n_in; (void)out_size;
  const float* values = (const float*)d_in[0];   // [Tv,B,V]
  const float* keys   = (const float*)d_in[2];   // [B,Tk,K]
  const float* w      = (const float*)d_in[3];   // [K,V]

  float* attn = (float*)d_out;                       // [B,Tk,Tv]
  float* outp = (float*)d_out + (long)NB_*TK_*TV_;   // [B,Tk,V]

  char* ws = (char*)d_ws;
  const long MB = 1024L*1024L;
  const bool fused = ws_size >= (size_t)(340*MB);
  const size_t LDSB = 131072;

  if (fused){
    ushort* kh   = (ushort*)(ws);                // 64MB keys fp16 (reused: v2)
    ushort* vbt  = (ushort*)(ws + 64*MB);        // 64MB vbt [B,V,Tv] fp16
    ushort* plh  = (ushort*)(ws + 128*MB);       // 64MB pl fp16
    ushort* adb  = (ushort*)(ws + 192*MB);       // 128MB shifted fp16 logits
    float*  pm   = (float*)(ws + 320*MB);        // 4MB partial max
    float*  psum = (float*)(ws + 324*MB);        // 4MB partial sum-exp
    float*  dsh2 = (float*)(ws + 328*MB);        // 4MB folded shift
    ushort* wth  = (ushort*)(ws + 332*MB);       // 2MB wT fp16
    ushort* v2   = kh;
    ushort* p16  = adb;   // pexp reads h and writes P16 at the SAME index -> in-place safe

    cvt_h_k<<<2048,256,0,stream>>>(keys, kh, (long)NB_*TK_*NK_/4);
    wtrans_k<<<dim3(32,32),dim3(32,8),0,stream>>>(w, wth);
    gemm8_k<1><<<dim3(NV_/256, TK_/256, NB_),512,LDSB,stream>>>(
        kh, wth, nullptr, plh, nullptr, nullptr,
        NV_, NK_, (long)TK_*NK_, 0L, (long)TK_*NV_);
    vboth_k<<<dim3(TV_/32, NV_/32, NB_),dim3(32,8),0,stream>>>(values, v2, vbt);
    // GEMM2: shifted fp16 logits + softmax partials
    gemm8_k<2><<<dim3(TV_/256, TK_/256, NB_),512,LDSB,stream>>>(
        plh, v2, nullptr, adb, pm, psum,
        TV_, NV_, (long)TK_*NV_, (long)TV_*NV_, (long)TK_*TV_);
    rs_k<<<NB_*TK_/256,256,0,stream>>>(pm, psum, dsh2);
    // exp pass: attn fp32 + P16 fp16 (in-place over adb)
    pexp_k<<<2048,256,0,stream>>>(adb, dsh2, attn, p16);
    // GEMM3: out = P16 * vbt^T
    gemm8_k<0><<<dim3(NV_/256, TK_/256, NB_),512,LDSB,stream>>>(
        p16, vbt, outp, nullptr, nullptr, nullptr,
        NV_, TV_, (long)TK_*TV_, (long)NV_*TV_, (long)TK_*NV_);
  } else {
    // Fallback: R4 flow (258MB layout)
    ushort* kh  = (ushort*)(ws);
    ushort* vbt = (ushort*)(ws + 64*MB);
    ushort* plh = (ushort*)(ws + 128*MB);
    ushort* adb = (ushort*)(ws + 128*MB);
    ushort* wth = (ushort*)(ws + 256*MB);
    ushort* v2  = kh;

    cvt_h_k<<<2048,256,0,stream>>>(keys, kh, (long)NB_*TK_*NK_/4);
    wtrans_k<<<dim3(32,32),dim3(32,8),0,stream>>>(w, wth);
    gemm8_k<1><<<dim3(NV_/256, TK_/256, NB_),512,LDSB,stream>>>(
        kh, wth, nullptr, plh, nullptr, nullptr,
        NV_, NK_, (long)TK_*NK_, 0L, (long)TK_*NV_);
    vboth_k<<<dim3(TV_/32, NV_/32, NB_),dim3(32,8),0,stream>>>(values, v2, vbt);
    gemm8_k<0><<<dim3(TV_/256, TK_/256, NB_),512,LDSB,stream>>>(
        plh, v2, attn, nullptr, nullptr, nullptr,
        TV_, NV_, (long)TK_*NV_, (long)TV_*NV_, (long)TK_*TV_);
    softmax_k<<<NB_*TK_,256,0,stream>>>(attn, adb);
    gemm8_k<0><<<dim3(NV_/256, TK_/256, NB_),512,LDSB,stream>>>(
        adb, vbt, outp, nullptr, nullptr, nullptr,
        NV_, TV_, (long)TK_*TV_, (long)NV_*TV_, (long)TK_*NV_);
  }
}

// Round 10
// 610.251 us; speedup vs baseline: 1.1503x; 1.1503x over previous
//
#include <hip/hip_runtime.h>

// Problem constants (from reference)
#define TV_ 2048
#define NB_ 16
#define NV_ 1024
#define TK_ 2048
#define NK_ 1024

typedef float    f32x4 __attribute__((ext_vector_type(4)));
typedef float    fl4   __attribute__((ext_vector_type(4)));
typedef _Float16 hfx8  __attribute__((ext_vector_type(8)));
typedef ushort   us8   __attribute__((ext_vector_type(8)));

static __device__ __forceinline__ ushort f2h(float f){
  _Float16 h = (_Float16)f;               // RN-even
  return __builtin_bit_cast(ushort, h);
}
static __device__ __forceinline__ float h2f(ushort u){
  return (float)__builtin_bit_cast(_Float16, u);
}

// ---------------- elementwise convert: fp32 -> fp16 ----------------
__global__ __launch_bounds__(256) void cvt_h_k(const float* __restrict__ x,
                                               ushort* __restrict__ y, long n4){
  long i = (long)blockIdx.x*256 + threadIdx.x;
  const long stride = (long)gridDim.x*256;
  for (; i < n4; i += stride){
    fl4 v = ((const fl4*)x)[i];
    ((ushort4*)y)[i] = make_ushort4(f2h(v[0]), f2h(v[1]), f2h(v[2]), f2h(v[3]));
  }
}

// ---------------- w [K,V] -> wT [V,K] fp16 ----------------
__global__ void wtrans_k(const float* __restrict__ w, ushort* __restrict__ wT){
  __shared__ float t[32][33];
  const int tx = threadIdx.x, ty = threadIdx.y;       // 32 x 8
  const int k0 = blockIdx.x*32, v0 = blockIdx.y*32;
#pragma unroll
  for (int r=0;r<4;++r) t[ty+8*r][tx] = w[(long)(k0+ty+8*r)*NV_ + v0+tx];
  __syncthreads();
#pragma unroll
  for (int r=0;r<4;++r)
    wT[(long)(v0+ty+8*r)*NK_ + k0+tx] = f2h(t[tx][ty+8*r]);
}

// ------- values [Tv,B,V] -> v2 [B,Tv,V] fp16 AND vbt [B,V,Tv] fp16, one read -------
__global__ void vboth_k(const float* __restrict__ vals,
                        ushort* __restrict__ v2, ushort* __restrict__ vbt){
  __shared__ float t[32][33];
  const int tx = threadIdx.x, ty = threadIdx.y;       // 32 x 8
  const int s0 = blockIdx.x*32, v0 = blockIdx.y*32, b = blockIdx.z;
#pragma unroll
  for (int r=0;r<4;++r){
    float x = vals[((long)(s0+ty+8*r)*NB_ + b)*NV_ + v0+tx];
    t[ty+8*r][tx] = x;
    v2[((long)b*TV_ + s0+ty+8*r)*NV_ + v0+tx] = f2h(x);
  }
  __syncthreads();
#pragma unroll
  for (int r=0;r<4;++r)
    vbt[((long)b*NV_ + v0+ty+8*r)*TV_ + s0+tx] = f2h(t[tx][ty+8*r]);
}

// =======================================================================
// 256x256 8-phase GEMM, 16x16x32 MFMA (R4/R7-verified KTILE: 8 independent
// MFMA chains of depth 2 per phase — do NOT use 32x32 here, R8 showed the
// 2-chain/depth-4 dependency shape stalls the matrix pipe).
// No XCD swizzle (R9 isolates its cost vs R7).
// =======================================================================
static __device__ __forceinline__ hfx8 ldfrag(const ushort* base, int r, int q){
  const int off = r*128 + (((q ^ (r & 7)) & 7) << 4);
  return *(const hfx8*)((const char*)base + off);
}

#define SAOFF(b,h) (((b)*2+(h))*8192)
#define SBOFF(b,h) (32768 + ((b)*2+(h))*8192)

#define STAGE(Xp, hb, t, ldsoff) do { \
  _Pragma("unroll") \
  for (int c_=0;c_<2;++c_) \
    __builtin_amdgcn_global_load_lds( \
      (const __attribute__((address_space(1))) unsigned*)((Xp) + (long)(hb)*128*K + (long)(t)*64 + soff[c_]), \
      (__attribute__((address_space(3))) unsigned*)(lds + (ldsoff) + chunk0[c_]*8), 16, 0, 0); \
} while(0)

#define VM4  asm volatile("s_waitcnt vmcnt(4)"  ::: "memory")
#define VM0  asm volatile("s_waitcnt vmcnt(0)"  ::: "memory")
#define NOPS (void)0

#define BARR() do { __builtin_amdgcn_s_barrier(); __builtin_amdgcn_sched_barrier(0); } while(0)

#define MFMA_SET(IB, JB, BREG) \
  _Pragma("unroll") for (int kk=0;kk<2;++kk) \
  _Pragma("unroll") for (int i=0;i<4;++i) \
  _Pragma("unroll") for (int j=0;j<2;++j) \
    acc[(IB)+i][(JB)+j] = __builtin_amdgcn_mfma_f32_16x16x32_f16(aR[i][kk], BREG[j][kk], acc[(IB)+i][(JB)+j], 0,0,0)

// One K-tile = 4 phases. S0..S3: stage statements; EW: end wait (vmcnt) at PH3.
#define KTILE(BUF, S0, S1, S2, S3, EW) do { \
  const ushort* sa_ = lds + SAOFF(BUF, wr); \
  const ushort* sb_ = lds + SBOFF(BUF, (wc>>1)); \
  const int brow_ = (wc&1)*64; \
  /* PH0 */ \
  _Pragma("unroll") for (int i=0;i<4;++i) _Pragma("unroll") for (int kk=0;kk<2;++kk) \
    aR[i][kk] = ldfrag(sa_, i*16+lm, lq+kk*4); \
  _Pragma("unroll") for (int j=0;j<2;++j) _Pragma("unroll") for (int kk=0;kk<2;++kk) \
    b01[j][kk] = ldfrag(sb_, brow_ + j*16 + lm, lq+kk*4); \
  S0; \
  BARR(); \
  __builtin_amdgcn_s_setprio(1); \
  MFMA_SET(0, 0, b01); \
  __builtin_amdgcn_s_setprio(0); \
  BARR(); \
  /* PH1 */ \
  _Pragma("unroll") for (int j=0;j<2;++j) _Pragma("unroll") for (int kk=0;kk<2;++kk) \
    b23[j][kk] = ldfrag(sb_, brow_ + (2+j)*16 + lm, lq+kk*4); \
  S1; \
  BARR(); \
  __builtin_amdgcn_s_setprio(1); \
  MFMA_SET(0, 2, b23); \
  __builtin_amdgcn_s_setprio(0); \
  BARR(); \
  /* PH2 */ \
  _Pragma("unroll") for (int i=0;i<4;++i) _Pragma("unroll") for (int kk=0;kk<2;++kk) \
    aR[i][kk] = ldfrag(sa_, (4+i)*16+lm, lq+kk*4); \
  S2; \
  BARR(); \
  __builtin_amdgcn_s_setprio(1); \
  MFMA_SET(4, 2, b23); \
  __builtin_amdgcn_s_setprio(0); \
  BARR(); \
  /* PH3 */ \
  S3; \
  BARR(); \
  __builtin_amdgcn_s_setprio(1); \
  MFMA_SET(4, 0, b01); \
  __builtin_amdgcn_s_setprio(0); \
  EW; \
  BARR(); \
} while(0)

// ---------------- generic GEMM ----------------
// OUTMODE: 0 = fp32 C; 1 = fp16 Ch; 2 = fp16 Ch shifted by per-wave 64-col max
//          + softmax partials (pm, ps).
template<int OUTMODE>
__global__ __launch_bounds__(512, 2)
void gemm8_k(const ushort* __restrict__ A, const ushort* __restrict__ BT,
             float* __restrict__ C, ushort* __restrict__ Ch,
             float* __restrict__ pm, float* __restrict__ ps,
             int N, int K, long sA, long sB, long sC)
{
  extern __shared__ ushort lds[];

  const int tid  = threadIdx.x;
  const int lane = tid & 63;
  const int w    = tid >> 6;
  const int wr   = w >> 2;
  const int wc   = w & 3;
  const int lm   = lane & 15, lq = lane >> 4;
  const int bz   = blockIdx.z;
  const long m0  = (long)blockIdx.y * 256;
  const long n0  = (long)blockIdx.x * 256;

  const ushort* Ap = A  + (long)bz*sA + m0*K;
  const ushort* Bp = BT + (long)bz*sB + n0*K;

  int chunk0[2], soff[2];
#pragma unroll
  for (int c=0;c<2;++c){
    chunk0[c] = (w<<7) + (c<<6);
    const int idx = chunk0[c] + lane;
    const int row = idx >> 3, sl = idx & 7;
    soff[c] = row*K + ((sl ^ (row & 7)) << 3);
  }

  f32x4 acc[8][4];
#pragma unroll
  for (int i=0;i<8;++i)
#pragma unroll
    for (int j=0;j<4;++j) acc[i][j] = (f32x4){0.f,0.f,0.f,0.f};

  hfx8 aR[4][2], b01[2][2], b23[2][2];

  const int NT = K >> 6;

  STAGE(Ap, 0, 0, SAOFF(0,0));
  STAGE(Ap, 1, 0, SAOFF(0,1));
  STAGE(Bp, 0, 0, SBOFF(0,0));
  STAGE(Bp, 1, 0, SBOFF(0,1));
  STAGE(Bp, 0, 1, SBOFF(1,0));
  STAGE(Ap, 0, 1, SAOFF(1,0));
  VM4;
  BARR();

  for (int u=0; u <= NT-4; u+=2){
    KTILE(0,
          STAGE(Ap, 1, u+1, SAOFF(1,1)),
          STAGE(Bp, 1, u+1, SBOFF(1,1)),
          STAGE(Bp, 0, u+2, SBOFF(0,0)),
          STAGE(Ap, 0, u+2, SAOFF(0,0)),
          VM4);
    KTILE(1,
          STAGE(Ap, 1, u+2, SAOFF(0,1)),
          STAGE(Bp, 1, u+2, SBOFF(0,1)),
          STAGE(Bp, 0, u+3, SBOFF(1,0)),
          STAGE(Ap, 0, u+3, SAOFF(1,0)),
          VM4);
  }
  KTILE(0,
        STAGE(Ap, 1, NT-1, SAOFF(1,1)),
        STAGE(Bp, 1, NT-1, SBOFF(1,1)),
        NOPS, NOPS, VM0);
  KTILE(1, NOPS, NOPS, NOPS, NOPS, NOPS);

  const long cb = (long)bz*sC;
  if constexpr (OUTMODE == 2){
#pragma unroll
    for (int i=0;i<8;++i){
      float mts[4];
#pragma unroll
      for (int g=0; g<4; ++g){
        float mt = fmaxf(fmaxf(acc[i][0][g], acc[i][1][g]), fmaxf(acc[i][2][g], acc[i][3][g]));
#pragma unroll
        for (int off=1; off<16; off<<=1) mt = fmaxf(mt, __shfl_xor(mt, off));
        float se = 0.f;
#pragma unroll
        for (int j=0;j<4;++j) se += __expf(acc[i][j][g] - mt);
#pragma unroll
        for (int off=1; off<16; off<<=1) se += __shfl_xor(se, off);
        if (lm == 0){
          const long rg = (long)bz*TK_ + m0 + wr*128 + i*16 + lq*4 + g;
          pm[rg*32 + blockIdx.x*4 + wc] = mt;
          ps[rg*32 + blockIdx.x*4 + wc] = se;
        }
        mts[g] = mt;
      }
#pragma unroll
      for (int j=0;j<4;++j)
#pragma unroll
        for (int g=0; g<4; ++g){
          const long gm = m0 + wr*128 + i*16 + lq*4 + g;
          const long gn = n0 + wc*64  + j*16 + lm;
          Ch[cb + gm*N + gn] = f2h(acc[i][j][g] - mts[g]);
        }
    }
  } else {
#pragma unroll
    for (int i=0;i<8;++i)
#pragma unroll
      for (int j=0;j<4;++j)
#pragma unroll
        for (int g=0; g<4; ++g){
          const long gm = m0 + wr*128 + i*16 + lq*4 + g;
          const long gn = n0 + wc*64  + j*16 + lm;
          const long o = cb + gm*N + gn;
          if constexpr (OUTMODE == 1) Ch[o] = f2h(acc[i][j][g]);
          else                        C[o]  = acc[i][j][g];
        }
  }
}

// ---- row-stat reduce: 32 (max,sumexp) partials -> dsh2[r][p] = mt - m - ln(s) ----
__global__ __launch_bounds__(256) void rs_k(const float* __restrict__ pm,
                                            const float* __restrict__ ps,
                                            float* __restrict__ dsh2){
  const long r = (long)blockIdx.x*256 + threadIdx.x;   // 32768 rows
  float pmv[32];
  float m = -3.4e38f;
#pragma unroll
  for (int p=0;p<32;++p){ pmv[p] = pm[r*32+p]; m = fmaxf(m, pmv[p]); }
  float s = 0.f;
#pragma unroll
  for (int p=0;p<32;++p) s += ps[r*32+p] * __expf(pmv[p] - m);
  const float lg = __logf(s);
#pragma unroll
  for (int p=0;p<32;++p) dsh2[r*32+p] = pmv[p] - m - lg;
}

// ---- streaming exp pass: P = exp(h + dsh2); writes attn fp32 + P16 fp16 ----
__global__ __launch_bounds__(256) void pexp_k(const ushort* __restrict__ h16,
                                              const float* __restrict__ dsh2,
                                              float* __restrict__ attn,
                                              ushort* __restrict__ p16){
  const long n8 = (long)NB_*TK_*TV_/8;
  long i = (long)blockIdx.x*256 + threadIdx.x;
  const long stride = (long)gridDim.x*256;
  for (; i < n8; i += stride){
    us8 hv = ((const us8*)h16)[i];
    const long row = i >> 8;               // Tv/8 = 256 8-elem chunks per row
    const int  c8  = (int)(i & 255);
    const float d = dsh2[row*32 + (c8>>3)];
    float p[8];
#pragma unroll
    for (int e=0;e<8;++e) p[e] = __expf(h2f((ushort)hv[e]) + d);
    fl4 q0 = {p[0],p[1],p[2],p[3]}, q1 = {p[4],p[5],p[6],p[7]};
    *(fl4*)(attn + i*8)     = q0;
    *(fl4*)(attn + i*8 + 4) = q1;
    us8 o;
#pragma unroll
    for (int e=0;e<8;++e) o[e] = f2h(p[e]);
    ((us8*)p16)[i] = o;
  }
}

// ---------------- row softmax (fallback path only) ----------------
__global__ __launch_bounds__(256) void softmax_k(float* __restrict__ lg, ushort* __restrict__ pb){
  const long base = (long)blockIdx.x * TV_;
  const int tid = threadIdx.x;
  const int lane = tid & 63, w = tid >> 6;
  float x[8];
  fl4 a = *(const fl4*)(lg + base + tid*8);
  fl4 b = *(const fl4*)(lg + base + tid*8 + 4);
  x[0]=a[0];x[1]=a[1];x[2]=a[2];x[3]=a[3];x[4]=b[0];x[5]=b[1];x[6]=b[2];x[7]=b[3];
  float m = x[0];
#pragma unroll
  for (int j=1;j<8;++j) m = fmaxf(m, x[j]);
#pragma unroll
  for (int off=32; off; off>>=1) m = fmaxf(m, __shfl_xor(m, off));
  __shared__ float rm[4], rs[4];
  if (lane==0) rm[w]=m;
  __syncthreads();
  m = fmaxf(fmaxf(rm[0],rm[1]), fmaxf(rm[2],rm[3]));
  float s = 0.f;
#pragma unroll
  for (int j=0;j<8;++j){ x[j] = __expf(x[j]-m); s += x[j]; }
#pragma unroll
  for (int off=32; off; off>>=1) s += __shfl_xor(s, off);
  if (lane==0) rs[w]=s;
  __syncthreads();
  s = rs[0]+rs[1]+rs[2]+rs[3];
  const float inv = 1.f/s;
  fl4 p0 = {x[0]*inv, x[1]*inv, x[2]*inv, x[3]*inv};
  fl4 p1 = {x[4]*inv, x[5]*inv, x[6]*inv, x[7]*inv};
  *(fl4*)(lg + base + tid*8)     = p0;
  *(fl4*)(lg + base + tid*8 + 4) = p1;
  *(ushort4*)(pb + base + tid*8)     = make_ushort4(f2h(p0[0]),f2h(p0[1]),f2h(p0[2]),f2h(p0[3]));
  *(ushort4*)(pb + base + tid*8 + 4) = make_ushort4(f2h(p1[0]),f2h(p1[1]),f2h(p1[2]),f2h(p1[3]));
}

extern "C" void kernel_launch(void* const* d_in, const int* in_sizes, int n_in,
                              void* d_out, int out_size, void* d_ws, size_t ws_size,
                              hipStream_t stream){
  (void)in_sizes; (void)n_in; (void)out_size;
  const float* values = (const float*)d_in[0];   // [Tv,B,V]
  const float* keys   = (const float*)d_in[2];   // [B,Tk,K]
  const float* w      = (const float*)d_in[3];   // [K,V]

  float* attn = (float*)d_out;                       // [B,Tk,Tv]
  float* outp = (float*)d_out + (long)NB_*TK_*TV_;   // [B,Tk,V]

  char* ws = (char*)d_ws;
  const long MB = 1024L*1024L;
  const bool fused = ws_size >= (size_t)(340*MB);
  const size_t LDSB = 131072;

  if (fused){
    ushort* kh   = (ushort*)(ws);                // 64MB keys fp16 (reused: v2)
    ushort* vbt  = (ushort*)(ws + 64*MB);        // 64MB vbt [B,V,Tv] fp16
    ushort* plh  = (ushort*)(ws + 128*MB);       // 64MB pl fp16
    ushort* adb  = (ushort*)(ws + 192*MB);       // 128MB shifted fp16 logits
    float*  pm   = (float*)(ws + 320*MB);        // 4MB partial max
    float*  psum = (float*)(ws + 324*MB);        // 4MB partial sum-exp
    float*  dsh2 = (float*)(ws + 328*MB);        // 4MB folded shift
    ushort* wth  = (ushort*)(ws + 332*MB);       // 2MB wT fp16
    ushort* v2   = kh;
    ushort* p16  = adb;   // pexp reads h and writes P16 at the SAME index -> in-place safe

    cvt_h_k<<<2048,256,0,stream>>>(keys, kh, (long)NB_*TK_*NK_/4);
    wtrans_k<<<dim3(32,32),dim3(32,8),0,stream>>>(w, wth);
    gemm8_k<1><<<dim3(NV_/256, TK_/256, NB_),512,LDSB,stream>>>(
        kh, wth, nullptr, plh, nullptr, nullptr,
        NV_, NK_, (long)TK_*NK_, 0L, (long)TK_*NV_);
    vboth_k<<<dim3(TV_/32, NV_/32, NB_),dim3(32,8),0,stream>>>(values, v2, vbt);
    // GEMM2: shifted fp16 logits + softmax partials
    gemm8_k<2><<<dim3(TV_/256, TK_/256, NB_),512,LDSB,stream>>>(
        plh, v2, nullptr, adb, pm, psum,
        TV_, NV_, (long)TK_*NV_, (long)TV_*NV_, (long)TK_*TV_);
    rs_k<<<NB_*TK_/256,256,0,stream>>>(pm, psum, dsh2);
    // exp pass: attn fp32 + P16 fp16 (in-place over adb)
    pexp_k<<<2048,256,0,stream>>>(adb, dsh2, attn, p16);
    // GEMM3: out = P16 * vbt^T
    gemm8_k<0><<<dim3(NV_/256, TK_/256, NB_),512,LDSB,stream>>>(
        p16, vbt, outp, nullptr, nullptr, nullptr,
        NV_, TV_, (long)TK_*TV_, (long)NV_*TV_, (long)TK_*NV_);
  } else {
    // Fallback: R4 flow (258MB layout)
    ushort* kh  = (ushort*)(ws);
    ushort* vbt = (ushort*)(ws + 64*MB);
    ushort* plh = (ushort*)(ws + 128*MB);
    ushort* adb = (ushort*)(ws + 128*MB);
    ushort* wth = (ushort*)(ws + 256*MB);
    ushort* v2  = kh;

    cvt_h_k<<<2048,256,0,stream>>>(keys, kh, (long)NB_*TK_*NK_/4);
    wtrans_k<<<dim3(32,32),dim3(32,8),0,stream>>>(w, wth);
    gemm8_k<1><<<dim3(NV_/256, TK_/256, NB_),512,LDSB,stream>>>(
        kh, wth, nullptr, plh, nullptr, nullptr,
        NV_, NK_, (long)TK_*NK_, 0L, (long)TK_*NV_);
    vboth_k<<<dim3(TV_/32, NV_/32, NB_),dim3(32,8),0,stream>>>(values, v2, vbt);
    gemm8_k<0><<<dim3(TV_/256, TK_/256, NB_),512,LDSB,stream>>>(
        plh, v2, attn, nullptr, nullptr, nullptr,
        TV_, NV_, (long)TK_*NV_, (long)TV_*NV_, (long)TK_*TV_);
    softmax_k<<<NB_*TK_,256,0,stream>>>(attn, adb);
    gemm8_k<0><<<dim3(NV_/256, TK_/256, NB_),512,LDSB,stream>>>(
        adb, vbt, outp, nullptr, nullptr, nullptr,
        NV_, TV_, (long)TK_*TV_, (long)NV_*TV_, (long)TK_*NV_);
  }
}

// Round 11
// 608.930 us; speedup vs baseline: 1.1528x; 1.0022x over previous
//
#include <hip/hip_runtime.h>

// Problem constants (from reference)
#define TV_ 2048
#define NB_ 16
#define NV_ 1024
#define TK_ 2048
#define NK_ 1024

typedef float    f32x4 __attribute__((ext_vector_type(4)));
typedef float    fl4   __attribute__((ext_vector_type(4)));
typedef _Float16 hfx8  __attribute__((ext_vector_type(8)));
typedef ushort   us8   __attribute__((ext_vector_type(8)));

static __device__ __forceinline__ ushort f2h(float f){
  _Float16 h = (_Float16)f;               // RN-even
  return __builtin_bit_cast(ushort, h);
}
static __device__ __forceinline__ float h2f(ushort u){
  return (float)__builtin_bit_cast(_Float16, u);
}

// ---------------- elementwise convert: fp32 -> fp16 ----------------
__global__ __launch_bounds__(256) void cvt_h_k(const float* __restrict__ x,
                                               ushort* __restrict__ y, long n4){
  long i = (long)blockIdx.x*256 + threadIdx.x;
  const long stride = (long)gridDim.x*256;
  for (; i < n4; i += stride){
    fl4 v = ((const fl4*)x)[i];
    ((ushort4*)y)[i] = make_ushort4(f2h(v[0]), f2h(v[1]), f2h(v[2]), f2h(v[3]));
  }
}

// ---------------- w [K,V] -> wT [V,K] fp16 ----------------
__global__ void wtrans_k(const float* __restrict__ w, ushort* __restrict__ wT){
  __shared__ float t[32][33];
  const int tx = threadIdx.x, ty = threadIdx.y;       // 32 x 8
  const int k0 = blockIdx.x*32, v0 = blockIdx.y*32;
#pragma unroll
  for (int r=0;r<4;++r) t[ty+8*r][tx] = w[(long)(k0+ty+8*r)*NV_ + v0+tx];
  __syncthreads();
#pragma unroll
  for (int r=0;r<4;++r)
    wT[(long)(v0+ty+8*r)*NK_ + k0+tx] = f2h(t[tx][ty+8*r]);
}

// ------- values [Tv,B,V] -> v2 [B,Tv,V] fp16 AND vbt [B,V,Tv] fp16, one read -------
__global__ void vboth_k(const float* __restrict__ vals,
                        ushort* __restrict__ v2, ushort* __restrict__ vbt){
  __shared__ float t[32][33];
  const int tx = threadIdx.x, ty = threadIdx.y;       // 32 x 8
  const int s0 = blockIdx.x*32, v0 = blockIdx.y*32, b = blockIdx.z;
#pragma unroll
  for (int r=0;r<4;++r){
    float x = vals[((long)(s0+ty+8*r)*NB_ + b)*NV_ + v0+tx];
    t[ty+8*r][tx] = x;
    v2[((long)b*TV_ + s0+ty+8*r)*NV_ + v0+tx] = f2h(x);
  }
  __syncthreads();
#pragma unroll
  for (int r=0;r<4;++r)
    vbt[((long)b*NV_ + v0+ty+8*r)*TV_ + s0+tx] = f2h(t[tx][ty+8*r]);
}

// =======================================================================
// 256x256 GEMM, 16x16x32 MFMA — R9 kernel with REDUCED BARRIERS (3/tile).
// Hazard audit (R10): only three block-wide syncs are required per K-tile:
//   B1: after b01/b23 LDS reads landed (lgkmcnt 0), before S2 overwrites
//       current-buf B0 (read by wc01 waves in this tile).
//   B3: after a4-7 LDS reads landed, before S3 overwrites current-buf A0.
//   B6: tile boundary — per-wave EW (vmcnt) + barrier publishes staged halves.
// All other barriers in the R4-R9 KTILE were pure phase-lockstep; removing
// them lets waves desync so MFMA and LDS/VMEM issue overlap across waves.
// MFMA order, staging order, and the vmcnt ledger are unchanged.
// =======================================================================
static __device__ __forceinline__ hfx8 ldfrag(const ushort* base, int r, int q){
  const int off = r*128 + (((q ^ (r & 7)) & 7) << 4);
  return *(const hfx8*)((const char*)base + off);
}

#define SAOFF(b,h) (((b)*2+(h))*8192)
#define SBOFF(b,h) (32768 + ((b)*2+(h))*8192)

#define STAGE(Xp, hb, t, ldsoff) do { \
  _Pragma("unroll") \
  for (int c_=0;c_<2;++c_) \
    __builtin_amdgcn_global_load_lds( \
      (const __attribute__((address_space(1))) unsigned*)((Xp) + (long)(hb)*128*K + (long)(t)*64 + soff[c_]), \
      (__attribute__((address_space(3))) unsigned*)(lds + (ldsoff) + chunk0[c_]*8), 16, 0, 0); \
} while(0)

#define VM4  asm volatile("s_waitcnt vmcnt(4)"  ::: "memory")
#define VM0  asm volatile("s_waitcnt vmcnt(0)"  ::: "memory")
#define LGK0 asm volatile("s_waitcnt lgkmcnt(0)" ::: "memory")
#define NOPS (void)0

#define BARR() do { __builtin_amdgcn_s_barrier(); __builtin_amdgcn_sched_barrier(0); } while(0)

#define MFMA_SET(IB, JB, BREG) \
  _Pragma("unroll") for (int kk=0;kk<2;++kk) \
  _Pragma("unroll") for (int i=0;i<4;++i) \
  _Pragma("unroll") for (int j=0;j<2;++j) \
    acc[(IB)+i][(JB)+j] = __builtin_amdgcn_mfma_f32_16x16x32_f16(aR[i][kk], BREG[j][kk], acc[(IB)+i][(JB)+j], 0,0,0)

// One K-tile, 3-barrier schedule. S0..S3: stage statements; EW: end vmcnt wait.
#define KTILE(BUF, S0, S1, S2, S3, EW) do { \
  const ushort* sa_ = lds + SAOFF(BUF, wr); \
  const ushort* sb_ = lds + SBOFF(BUF, (wc>>1)); \
  const int brow_ = (wc&1)*64; \
  /* loads a0-3 + b01 ; S0 ; MFMA quadrant (0,0) */ \
  _Pragma("unroll") for (int i=0;i<4;++i) _Pragma("unroll") for (int kk=0;kk<2;++kk) \
    aR[i][kk] = ldfrag(sa_, i*16+lm, lq+kk*4); \
  _Pragma("unroll") for (int j=0;j<2;++j) _Pragma("unroll") for (int kk=0;kk<2;++kk) \
    b01[j][kk] = ldfrag(sb_, brow_ + j*16 + lm, lq+kk*4); \
  S0; \
  __builtin_amdgcn_s_setprio(1); \
  MFMA_SET(0, 0, b01); \
  __builtin_amdgcn_s_setprio(0); \
  /* loads b23 ; S1 ; MFMA quadrant (0,2) */ \
  _Pragma("unroll") for (int j=0;j<2;++j) _Pragma("unroll") for (int kk=0;kk<2;++kk) \
    b23[j][kk] = ldfrag(sb_, brow_ + (2+j)*16 + lm, lq+kk*4); \
  S1; \
  __builtin_amdgcn_s_setprio(1); \
  MFMA_SET(0, 2, b23); \
  __builtin_amdgcn_s_setprio(0); \
  LGK0; \
  BARR();   /* B1: all waves' B reads landed -> S2 may overwrite B0 */ \
  /* loads a4-7 ; S2 ; MFMA quadrant (4,2) */ \
  _Pragma("unroll") for (int i=0;i<4;++i) _Pragma("unroll") for (int kk=0;kk<2;++kk) \
    aR[i][kk] = ldfrag(sa_, (4+i)*16+lm, lq+kk*4); \
  S2; \
  __builtin_amdgcn_s_setprio(1); \
  MFMA_SET(4, 2, b23); \
  __builtin_amdgcn_s_setprio(0); \
  LGK0; \
  BARR();   /* B3: all waves' A reads landed -> S3 may overwrite A0 */ \
  /* S3 ; MFMA quadrant (4,0) */ \
  S3; \
  __builtin_amdgcn_s_setprio(1); \
  MFMA_SET(4, 0, b01); \
  __builtin_amdgcn_s_setprio(0); \
  EW; \
  BARR();   /* B6: tile boundary (publishes staged halves of t+1) */ \
} while(0)

// ---------------- generic GEMM ----------------
// OUTMODE: 0 = fp32 C; 1 = fp16 Ch; 2 = fp16 Ch shifted by per-wave 64-col max
//          + softmax partials (pm, ps).
template<int OUTMODE>
__global__ __launch_bounds__(512, 2)
void gemm8_k(const ushort* __restrict__ A, const ushort* __restrict__ BT,
             float* __restrict__ C, ushort* __restrict__ Ch,
             float* __restrict__ pm, float* __restrict__ ps,
             int N, int K, long sA, long sB, long sC)
{
  extern __shared__ ushort lds[];

  const int tid  = threadIdx.x;
  const int lane = tid & 63;
  const int w    = tid >> 6;
  const int wr   = w >> 2;
  const int wc   = w & 3;
  const int lm   = lane & 15, lq = lane >> 4;
  const int bz   = blockIdx.z;
  const long m0  = (long)blockIdx.y * 256;
  const long n0  = (long)blockIdx.x * 256;

  const ushort* Ap = A  + (long)bz*sA + m0*K;
  const ushort* Bp = BT + (long)bz*sB + n0*K;

  int chunk0[2], soff[2];
#pragma unroll
  for (int c=0;c<2;++c){
    chunk0[c] = (w<<7) + (c<<6);
    const int idx = chunk0[c] + lane;
    const int row = idx >> 3, sl = idx & 7;
    soff[c] = row*K + ((sl ^ (row & 7)) << 3);
  }

  f32x4 acc[8][4];
#pragma unroll
  for (int i=0;i<8;++i)
#pragma unroll
    for (int j=0;j<4;++j) acc[i][j] = (f32x4){0.f,0.f,0.f,0.f};

  hfx8 aR[4][2], b01[2][2], b23[2][2];

  const int NT = K >> 6;

  STAGE(Ap, 0, 0, SAOFF(0,0));
  STAGE(Ap, 1, 0, SAOFF(0,1));
  STAGE(Bp, 0, 0, SBOFF(0,0));
  STAGE(Bp, 1, 0, SBOFF(0,1));
  STAGE(Bp, 0, 1, SBOFF(1,0));
  STAGE(Ap, 0, 1, SAOFF(1,0));
  VM4;
  BARR();

  for (int u=0; u <= NT-4; u+=2){
    KTILE(0,
          STAGE(Ap, 1, u+1, SAOFF(1,1)),
          STAGE(Bp, 1, u+1, SBOFF(1,1)),
          STAGE(Bp, 0, u+2, SBOFF(0,0)),
          STAGE(Ap, 0, u+2, SAOFF(0,0)),
          VM4);
    KTILE(1,
          STAGE(Ap, 1, u+2, SAOFF(0,1)),
          STAGE(Bp, 1, u+2, SBOFF(0,1)),
          STAGE(Bp, 0, u+3, SBOFF(1,0)),
          STAGE(Ap, 0, u+3, SAOFF(1,0)),
          VM4);
  }
  KTILE(0,
        STAGE(Ap, 1, NT-1, SAOFF(1,1)),
        STAGE(Bp, 1, NT-1, SBOFF(1,1)),
        NOPS, NOPS, VM0);
  KTILE(1, NOPS, NOPS, NOPS, NOPS, NOPS);

  const long cb = (long)bz*sC;
  if constexpr (OUTMODE == 2){
#pragma unroll
    for (int i=0;i<8;++i){
      float mts[4];
#pragma unroll
      for (int g=0; g<4; ++g){
        float mt = fmaxf(fmaxf(acc[i][0][g], acc[i][1][g]), fmaxf(acc[i][2][g], acc[i][3][g]));
#pragma unroll
        for (int off=1; off<16; off<<=1) mt = fmaxf(mt, __shfl_xor(mt, off));
        float se = 0.f;
#pragma unroll
        for (int j=0;j<4;++j) se += __expf(acc[i][j][g] - mt);
#pragma unroll
        for (int off=1; off<16; off<<=1) se += __shfl_xor(se, off);
        if (lm == 0){
          const long rg = (long)bz*TK_ + m0 + wr*128 + i*16 + lq*4 + g;
          pm[rg*32 + blockIdx.x*4 + wc] = mt;
          ps[rg*32 + blockIdx.x*4 + wc] = se;
        }
        mts[g] = mt;
      }
#pragma unroll
      for (int j=0;j<4;++j)
#pragma unroll
        for (int g=0; g<4; ++g){
          const long gm = m0 + wr*128 + i*16 + lq*4 + g;
          const long gn = n0 + wc*64  + j*16 + lm;
          Ch[cb + gm*N + gn] = f2h(acc[i][j][g] - mts[g]);
        }
    }
  } else {
#pragma unroll
    for (int i=0;i<8;++i)
#pragma unroll
      for (int j=0;j<4;++j)
#pragma unroll
        for (int g=0; g<4; ++g){
          const long gm = m0 + wr*128 + i*16 + lq*4 + g;
          const long gn = n0 + wc*64  + j*16 + lm;
          const long o = cb + gm*N + gn;
          if constexpr (OUTMODE == 1) Ch[o] = f2h(acc[i][j][g]);
          else                        C[o]  = acc[i][j][g];
        }
  }
}

// ---- row-stat reduce: 32 (max,sumexp) partials -> dsh2[r][p] = mt - m - ln(s) ----
__global__ __launch_bounds__(256) void rs_k(const float* __restrict__ pm,
                                            const float* __restrict__ ps,
                                            float* __restrict__ dsh2){
  const long r = (long)blockIdx.x*256 + threadIdx.x;   // 32768 rows
  float pmv[32];
  float m = -3.4e38f;
#pragma unroll
  for (int p=0;p<32;++p){ pmv[p] = pm[r*32+p]; m = fmaxf(m, pmv[p]); }
  float s = 0.f;
#pragma unroll
  for (int p=0;p<32;++p) s += ps[r*32+p] * __expf(pmv[p] - m);
  const float lg = __logf(s);
#pragma unroll
  for (int p=0;p<32;++p) dsh2[r*32+p] = pmv[p] - m - lg;
}

// ---- streaming exp pass: P = exp(h + dsh2); writes attn fp32 + P16 fp16 ----
__global__ __launch_bounds__(256) void pexp_k(const ushort* __restrict__ h16,
                                              const float* __restrict__ dsh2,
                                              float* __restrict__ attn,
                                              ushort* __restrict__ p16){
  const long n8 = (long)NB_*TK_*TV_/8;
  long i = (long)blockIdx.x*256 + threadIdx.x;
  const long stride = (long)gridDim.x*256;
  for (; i < n8; i += stride){
    us8 hv = ((const us8*)h16)[i];
    const long row = i >> 8;               // Tv/8 = 256 8-elem chunks per row
    const int  c8  = (int)(i & 255);
    const float d = dsh2[row*32 + (c8>>3)];
    float p[8];
#pragma unroll
    for (int e=0;e<8;++e) p[e] = __expf(h2f((ushort)hv[e]) + d);
    fl4 q0 = {p[0],p[1],p[2],p[3]}, q1 = {p[4],p[5],p[6],p[7]};
    *(fl4*)(attn + i*8)     = q0;
    *(fl4*)(attn + i*8 + 4) = q1;
    us8 o;
#pragma unroll
    for (int e=0;e<8;++e) o[e] = f2h(p[e]);
    ((us8*)p16)[i] = o;
  }
}

// ---------------- row softmax (fallback path only) ----------------
__global__ __launch_bounds__(256) void softmax_k(float* __restrict__ lg, ushort* __restrict__ pb){
  const long base = (long)blockIdx.x * TV_;
  const int tid = threadIdx.x;
  const int lane = tid & 63, w = tid >> 6;
  float x[8];
  fl4 a = *(const fl4*)(lg + base + tid*8);
  fl4 b = *(const fl4*)(lg + base + tid*8 + 4);
  x[0]=a[0];x[1]=a[1];x[2]=a[2];x[3]=a[3];x[4]=b[0];x[5]=b[1];x[6]=b[2];x[7]=b[3];
  float m = x[0];
#pragma unroll
  for (int j=1;j<8;++j) m = fmaxf(m, x[j]);
#pragma unroll
  for (int off=32; off; off>>=1) m = fmaxf(m, __shfl_xor(m, off));
  __shared__ float rm[4], rs[4];
  if (lane==0) rm[w]=m;
  __syncthreads();
  m = fmaxf(fmaxf(rm[0],rm[1]), fmaxf(rm[2],rm[3]));
  float s = 0.f;
#pragma unroll
  for (int j=0;j<8;++j){ x[j] = __expf(x[j]-m); s += x[j]; }
#pragma unroll
  for (int off=32; off; off>>=1) s += __shfl_xor(s, off);
  if (lane==0) rs[w]=s;
  __syncthreads();
  s = rs[0]+rs[1]+rs[2]+rs[3];
  const float inv = 1.f/s;
  fl4 p0 = {x[0]*inv, x[1]*inv, x[2]*inv, x[3]*inv};
  fl4 p1 = {x[4]*inv, x[5]*inv, x[6]*inv, x[7]*inv};
  *(fl4*)(lg + base + tid*8)     = p0;
  *(fl4*)(lg + base + tid*8 + 4) = p1;
  *(ushort4*)(pb + base + tid*8)     = make_ushort4(f2h(p0[0]),f2h(p0[1]),f2h(p0[2]),f2h(p0[3]));
  *(ushort4*)(pb + base + tid*8 + 4) = make_ushort4(f2h(p1[0]),f2h(p1[1]),f2h(p1[2]),f2h(p1[3]));
}

extern "C" void kernel_launch(void* const* d_in, const int* in_sizes, int n_in,
                              void* d_out, int out_size, void* d_ws, size_t ws_size,
                              hipStream_t stream){
  (void)in_sizes; (void)n_in; (void)out_size;
  const float* values = (const float*)d_in[0];   // [Tv,B,V]
  const float* keys   = (const float*)d_in[2];   // [B,Tk,K]
  const float* w      = (const float*)d_in[3];   // [K,V]

  float* attn = (float*)d_out;                       // [B,Tk,Tv]
  float* outp = (float*)d_out + (long)NB_*TK_*TV_;   // [B,Tk,V]

  char* ws = (char*)d_ws;
  const long MB = 1024L*1024L;
  const bool fused = ws_size >= (size_t)(340*MB);
  const size_t LDSB = 131072;

  if (fused){
    ushort* kh   = (ushort*)(ws);                // 64MB keys fp16 (reused: v2)
    ushort* vbt  = (ushort*)(ws + 64*MB);        // 64MB vbt [B,V,Tv] fp16
    ushort* plh  = (ushort*)(ws + 128*MB);       // 64MB pl fp16
    ushort* adb  = (ushort*)(ws + 192*MB);       // 128MB shifted fp16 logits
    float*  pm   = (float*)(ws + 320*MB);        // 4MB partial max
    float*  psum = (float*)(ws + 324*MB);        // 4MB partial sum-exp
    float*  dsh2 = (float*)(ws + 328*MB);        // 4MB folded shift
    ushort* wth  = (ushort*)(ws + 332*MB);       // 2MB wT fp16
    ushort* v2   = kh;
    ushort* p16  = adb;   // pexp reads h and writes P16 at the SAME index -> in-place safe

    cvt_h_k<<<2048,256,0,stream>>>(keys, kh, (long)NB_*TK_*NK_/4);
    wtrans_k<<<dim3(32,32),dim3(32,8),0,stream>>>(w, wth);
    gemm8_k<1><<<dim3(NV_/256, TK_/256, NB_),512,LDSB,stream>>>(
        kh, wth, nullptr, plh, nullptr, nullptr,
        NV_, NK_, (long)TK_*NK_, 0L, (long)TK_*NV_);
    vboth_k<<<dim3(TV_/32, NV_/32, NB_),dim3(32,8),0,stream>>>(values, v2, vbt);
    // GEMM2: shifted fp16 logits + softmax partials
    gemm8_k<2><<<dim3(TV_/256, TK_/256, NB_),512,LDSB,stream>>>(
        plh, v2, nullptr, adb, pm, psum,
        TV_, NV_, (long)TK_*NV_, (long)TV_*NV_, (long)TK_*TV_);
    rs_k<<<NB_*TK_/256,256,0,stream>>>(pm, psum, dsh2);
    // exp pass: attn fp32 + P16 fp16 (in-place over adb)
    pexp_k<<<2048,256,0,stream>>>(adb, dsh2, attn, p16);
    // GEMM3: out = P16 * vbt^T
    gemm8_k<0><<<dim3(NV_/256, TK_/256, NB_),512,LDSB,stream>>>(
        p16, vbt, outp, nullptr, nullptr, nullptr,
        NV_, TV_, (long)TK_*TV_, (long)NV_*TV_, (long)TK_*NV_);
  } else {
    // Fallback: R4 flow (258MB layout)
    ushort* kh  = (ushort*)(ws);
    ushort* vbt = (ushort*)(ws + 64*MB);
    ushort* plh = (ushort*)(ws + 128*MB);
    ushort* adb = (ushort*)(ws + 128*MB);
    ushort* wth = (ushort*)(ws + 256*MB);
    ushort* v2  = kh;

    cvt_h_k<<<2048,256,0,stream>>>(keys, kh, (long)NB_*TK_*NK_/4);
    wtrans_k<<<dim3(32,32),dim3(32,8),0,stream>>>(w, wth);
    gemm8_k<1><<<dim3(NV_/256, TK_/256, NB_),512,LDSB,stream>>>(
        kh, wth, nullptr, plh, nullptr, nullptr,
        NV_, NK_, (long)TK_*NK_, 0L, (long)TK_*NV_);
    vboth_k<<<dim3(TV_/32, NV_/32, NB_),dim3(32,8),0,stream>>>(values, v2, vbt);
    gemm8_k<0><<<dim3(TV_/256, TK_/256, NB_),512,LDSB,stream>>>(
        plh, v2, attn, nullptr, nullptr, nullptr,
        TV_, NV_, (long)TK_*NV_, (long)TV_*NV_, (long)TK_*TV_);
    softmax_k<<<NB_*TK_,256,0,stream>>>(attn, adb);
    gemm8_k<0><<<dim3(NV_/256, TK_/256, NB_),512,LDSB,stream>>>(
        adb, vbt, outp, nullptr, nullptr, nullptr,
        NV_, TV_, (long)TK_*TV_, (long)NV_*TV_, (long)TK_*NV_);
  }
}